// Round 3
// baseline (875.921 us; speedup 1.0000x reference)
//
#include <hip/hip_runtime.h>
#include <math.h>

#define NN 50000
#define NE 500000

typedef __attribute__((ext_vector_type(8))) short bf16x8;
typedef __attribute__((ext_vector_type(4))) float f32x4;

__device__ __forceinline__ float silu_f(float x) {
  return x / (1.0f + __expf(-x));
}
// fp32 -> bf16 (RNE)
__device__ __forceinline__ unsigned short f2bf(float x) {
  union { float f; unsigned u; } v;
  v.f = x;
  unsigned r = v.u + 0x7fffu + ((v.u >> 16) & 1u);
  return (unsigned short)(r >> 16);
}
// swizzled index into a [rows][64] bf16 tile: XOR 16B-unit with row&7
__device__ __forceinline__ int swz64(int row, int col) {
  return row * 64 + ((((col >> 3) ^ (row & 7)) << 3) | (col & 7));
}
// swizzled index into a [rows][32] bf16 tile: XOR 16B-unit with row&3
__device__ __forceinline__ int swz32(int row, int col) {
  return row * 32 + ((((col >> 3) ^ (row & 3)) << 3) | (col & 7));
}

// ---------------- Kernel A: up0 = h0@Wup0, up1[x] = h1[:,:,x]@Wup1 ----------
__global__ __launch_bounds__(256) void kup(
    const float* __restrict__ h, const float* __restrict__ Wup0,
    const float* __restrict__ Wup1, float* __restrict__ up0,
    float* __restrict__ up1) {
  __shared__ float shd[4][256];
  const int w = threadIdx.x >> 6, j = threadIdx.x & 63;
  const int n = blockIdx.x * 4 + w;
  const float* hr = h + (size_t)n * 256;
#pragma unroll
  for (int t = 0; t < 4; ++t) shd[w][t * 64 + j] = hr[t * 64 + j];
  __syncthreads();
  float a0 = 0.f, ax = 0.f, ay = 0.f, az = 0.f;
#pragma unroll 8
  for (int c = 0; c < 64; ++c) {
    float h0 = shd[w][c];
    float hx = shd[w][64 + 3 * c + 0];
    float hy = shd[w][64 + 3 * c + 1];
    float hz = shd[w][64 + 3 * c + 2];
    float w0 = Wup0[c * 64 + j];
    float w1 = Wup1[c * 64 + j];
    a0 = fmaf(h0, w0, a0);
    ax = fmaf(hx, w1, ax);
    ay = fmaf(hy, w1, ay);
    az = fmaf(hz, w1, az);
  }
  up0[(size_t)n * 64 + j] = a0;
  float* u1 = up1 + (size_t)n * 192 + j;
  u1[0] = ax;
  u1[64] = ay;
  u1[128] = az;
}

// ------------- Kernel B: MFMA edge MLP + tensor-product messages + scatter ----
// 512 threads = 8 waves share one staged weight set (68 KB LDS -> 2 blk/CU
// -> 16 waves/CU). Per wave: 16 edges via mfma_f32_16x16x32_bf16; no
// __syncthreads in the main loop (per-wave act tiles only).
__global__ __launch_bounds__(512) void kedge(
    const float* __restrict__ rbf, const int* __restrict__ eidx,
    const float* __restrict__ esh, const float* __restrict__ M1,
    const float* __restrict__ M2, const float* __restrict__ M3,
    const float* __restrict__ M4, const float* __restrict__ up0,
    const float* __restrict__ up1, float* __restrict__ msg0,
    float* __restrict__ msg1) {
  __shared__ unsigned short M1t[64 * 32];    // [out 64][in 32 (16 zero-pad)]
  __shared__ unsigned short M2t[64 * 64];    // [out][in]
  __shared__ unsigned short M3t[64 * 64];
  __shared__ unsigned short M4t[256 * 64];   // [out 256][in 64]
  __shared__ unsigned short actS[8][16 * 64];  // per-wave [edge 16][ch 64]
  const int tid = threadIdx.x;
  const int w = tid >> 6, l = tid & 63;
  const int c = l & 15, q = l >> 4;

  // ---- stage weights: coalesced global read, transposed+swizzled LDS write --
  for (int i = tid; i < 2048; i += 512) {
    int o = i >> 5, k = i & 31;
    M1t[swz32(o, k)] = (k < 16) ? f2bf(M1[k * 64 + o]) : (unsigned short)0;
  }
  for (int i = tid; i < 4096; i += 512) {
    int k = i >> 6, o = i & 63;
    M2t[swz64(o, k)] = f2bf(M2[i]);
    M3t[swz64(o, k)] = f2bf(M3[i]);
  }
  for (int i = tid; i < 16384; i += 512) {
    int k = i >> 8, o = i & 255;
    M4t[swz64(o, k)] = f2bf(M4[i]);
  }
  __syncthreads();

  unsigned short* act = actS[w];
  const float inv3 = 0.57735026918962576f;
  const int NW = NE / 16;  // 31250 wave-groups of 16 edges

  for (int grp = blockIdx.x; grp < (NW + 7) / 8; grp += gridDim.x) {
    const int gw = grp * 8 + w;
    if (gw >= NW) continue;
    const int eb = gw * 16;

    // ---- L1: rbf[16e][16] (K zero-padded to 32) -> act[16e][64] ----
    bf16x8 a1 = {};
    if (q < 2) {
      const float* p = rbf + (size_t)(eb + c) * 16 + q * 8;
      float4 f0 = *reinterpret_cast<const float4*>(p);
      float4 f1 = *reinterpret_cast<const float4*>(p + 4);
      a1[0] = (short)f2bf(f0.x); a1[1] = (short)f2bf(f0.y);
      a1[2] = (short)f2bf(f0.z); a1[3] = (short)f2bf(f0.w);
      a1[4] = (short)f2bf(f1.x); a1[5] = (short)f2bf(f1.y);
      a1[6] = (short)f2bf(f1.z); a1[7] = (short)f2bf(f1.w);
    }
    f32x4 acc[4];
#pragma unroll
    for (int nt = 0; nt < 4; ++nt) {
      int n = nt * 16 + c;
      bf16x8 b = *reinterpret_cast<const bf16x8*>(&M1t[n * 32 + ((q ^ (n & 3)) << 3)]);
      f32x4 z = {0.f, 0.f, 0.f, 0.f};
      acc[nt] = __builtin_amdgcn_mfma_f32_16x16x32_bf16(a1, b, z, 0, 0, 0);
    }
#pragma unroll
    for (int nt = 0; nt < 4; ++nt)
#pragma unroll
      for (int r = 0; r < 4; ++r)
        act[swz64(4 * q + r, nt * 16 + c)] = f2bf(silu_f(acc[nt][r]));

    // ---- L2: act -> act (64->64) ----
    {
      bf16x8 a0 = *reinterpret_cast<const bf16x8*>(&act[c * 64 + (((0 + q) ^ (c & 7)) << 3)]);
      bf16x8 a1b = *reinterpret_cast<const bf16x8*>(&act[c * 64 + (((4 + q) ^ (c & 7)) << 3)]);
#pragma unroll
      for (int nt = 0; nt < 4; ++nt) {
        int n = nt * 16 + c;
        bf16x8 b0 = *reinterpret_cast<const bf16x8*>(&M2t[n * 64 + (((0 + q) ^ (n & 7)) << 3)]);
        bf16x8 b1 = *reinterpret_cast<const bf16x8*>(&M2t[n * 64 + (((4 + q) ^ (n & 7)) << 3)]);
        f32x4 z = {0.f, 0.f, 0.f, 0.f};
        acc[nt] = __builtin_amdgcn_mfma_f32_16x16x32_bf16(a0, b0, z, 0, 0, 0);
        acc[nt] = __builtin_amdgcn_mfma_f32_16x16x32_bf16(a1b, b1, acc[nt], 0, 0, 0);
      }
#pragma unroll
      for (int nt = 0; nt < 4; ++nt)
#pragma unroll
        for (int r = 0; r < 4; ++r)
          act[swz64(4 * q + r, nt * 16 + c)] = f2bf(silu_f(acc[nt][r]));
    }
    // ---- L3: act -> act (64->64) ----
    {
      bf16x8 a0 = *reinterpret_cast<const bf16x8*>(&act[c * 64 + (((0 + q) ^ (c & 7)) << 3)]);
      bf16x8 a1b = *reinterpret_cast<const bf16x8*>(&act[c * 64 + (((4 + q) ^ (c & 7)) << 3)]);
#pragma unroll
      for (int nt = 0; nt < 4; ++nt) {
        int n = nt * 16 + c;
        bf16x8 b0 = *reinterpret_cast<const bf16x8*>(&M3t[n * 64 + (((0 + q) ^ (n & 7)) << 3)]);
        bf16x8 b1 = *reinterpret_cast<const bf16x8*>(&M3t[n * 64 + (((4 + q) ^ (n & 7)) << 3)]);
        f32x4 z = {0.f, 0.f, 0.f, 0.f};
        acc[nt] = __builtin_amdgcn_mfma_f32_16x16x32_bf16(a0, b0, z, 0, 0, 0);
        acc[nt] = __builtin_amdgcn_mfma_f32_16x16x32_bf16(a1b, b1, acc[nt], 0, 0, 0);
      }
#pragma unroll
      for (int nt = 0; nt < 4; ++nt)
#pragma unroll
        for (int r = 0; r < 4; ++r)
          act[swz64(4 * q + r, nt * 16 + c)] = f2bf(silu_f(acc[nt][r]));
    }
    // ---- L4: act -> tpw[16e][256] kept in registers (no silu) ----
    f32x4 t[16];
    {
      bf16x8 a0 = *reinterpret_cast<const bf16x8*>(&act[c * 64 + (((0 + q) ^ (c & 7)) << 3)]);
      bf16x8 a1b = *reinterpret_cast<const bf16x8*>(&act[c * 64 + (((4 + q) ^ (c & 7)) << 3)]);
#pragma unroll
      for (int nt = 0; nt < 16; ++nt) {
        int n = nt * 16 + c;
        bf16x8 b0 = *reinterpret_cast<const bf16x8*>(&M4t[n * 64 + (((0 + q) ^ (n & 7)) << 3)]);
        bf16x8 b1 = *reinterpret_cast<const bf16x8*>(&M4t[n * 64 + (((4 + q) ^ (n & 7)) << 3)]);
        f32x4 z = {0.f, 0.f, 0.f, 0.f};
        t[nt] = __builtin_amdgcn_mfma_f32_16x16x32_bf16(a0, b0, z, 0, 0, 0);
        t[nt] = __builtin_amdgcn_mfma_f32_16x16x32_bf16(a1b, b1, t[nt], 0, 0, 0);
      }
    }
    // ---- gather sender features, messages, atomic scatter ----
    // lane holds tpw rows (edges) 4q+r, channels j2*16+c: t[comp*4+j2][r]
#pragma unroll
    for (int r = 0; r < 4; ++r) {
      const int er = eb + 4 * q + r;
      const int sn = eidx[er];
      const int rv = eidx[NE + er];
      const float4 sh = *reinterpret_cast<const float4*>(esh + (size_t)er * 4);
      const float* u0 = up0 + (size_t)sn * 64;
      const float* u1 = up1 + (size_t)sn * 192;
      float* p0 = msg0 + (size_t)rv * 64;
      float* p1 = msg1 + (size_t)rv * 192;
#pragma unroll
      for (int j2 = 0; j2 < 4; ++j2) {
        const int ch = j2 * 16 + c;
        float x0 = u0[ch];
        float xx = u1[ch], xy = u1[64 + ch], xz = u1[128 + ch];
        float t0v = t[j2][r], t1v = t[4 + j2][r];
        float t2v = t[8 + j2][r], t3v = t[12 + j2][r];
        float dot = xx * sh.y + xy * sh.z + xz * sh.w;
        float m0 = t0v * x0 * sh.x + t3v * dot * inv3;
        float a1v = t1v * x0, b1v = t2v * sh.x;
        atomicAdd(p0 + ch, m0);
        atomicAdd(p1 + ch, fmaf(a1v, sh.y, b1v * xx));
        atomicAdd(p1 + 64 + ch, fmaf(a1v, sh.z, b1v * xy));
        atomicAdd(p1 + 128 + ch, fmaf(a1v, sh.w, b1v * xz));
      }
    }
  }
}

// ------------- Kernel C: node linear mixes + polynomial + output GEMVs + stats --
__global__ __launch_bounds__(256) void knode(
    const float* __restrict__ msg0, const float* __restrict__ msg1,
    const float* __restrict__ h, const float* __restrict__ Wl0,
    const float* __restrict__ Wl1, const float* __restrict__ Wsc0,
    const float* __restrict__ Wsc1, const float* __restrict__ Wc0,
    const float* __restrict__ Wc1, const float* __restrict__ WB0,
    const float* __restrict__ WB1, float* __restrict__ out,
    float* __restrict__ stat) {
  extern __shared__ float lds[];
  float* Wl0s = lds;           // 4096
  float* Wl1s = lds + 4096;
  float* Wsc0s = lds + 8192;
  float* Wsc1s = lds + 12288;
  float* stw = lds + 16384;    // 4 waves * 768
  const int tid = threadIdx.x, w = tid >> 6, j = tid & 63;
  for (int i = tid; i < 4096; i += 256) {
    Wl0s[i] = Wl0[i];
    Wl1s[i] = Wl1[i];
    Wsc0s[i] = Wsc0[i];
    Wsc1s[i] = Wsc1[i];
  }
  __syncthreads();
  float* st = stw + w * 768;
  float s_sum0 = 0.f, s_sq0 = 0.f, s_sum1 = 0.f;
  const float c00 = Wc0[j * 5 + 0], c01 = Wc0[j * 5 + 1], c02 = Wc0[j * 5 + 2],
              c03 = Wc0[j * 5 + 3], c04 = Wc0[j * 5 + 4];
  const float4 c1 = *reinterpret_cast<const float4*>(Wc1 + j * 4);

  for (int grp = blockIdx.x; grp < (NN / 4); grp += gridDim.x) {
    const int n = grp * 4 + w;
    st[j] = msg0[(size_t)n * 64 + j];
#pragma unroll
    for (int x = 0; x < 3; ++x)
      st[64 + x * 64 + j] = msg1[(size_t)n * 192 + x * 64 + j];
#pragma unroll
    for (int t = 0; t < 4; ++t)
      st[256 + t * 64 + j] = h[(size_t)n * 256 + t * 64 + j];
    __syncthreads();
    float A0 = 0, A1x = 0, A1y = 0, A1z = 0, sc0 = 0, sc1x = 0, sc1y = 0, sc1z = 0;
    for (int c4 = 0; c4 < 16; ++c4) {
      float4 m0v = *reinterpret_cast<const float4*>(st + c4 * 4);
      float4 mvx = *reinterpret_cast<const float4*>(st + 64 + c4 * 4);
      float4 mvy = *reinterpret_cast<const float4*>(st + 128 + c4 * 4);
      float4 mvz = *reinterpret_cast<const float4*>(st + 192 + c4 * 4);
      float4 h0v = *reinterpret_cast<const float4*>(st + 256 + c4 * 4);
#pragma unroll
      for (int kk = 0; kk < 4; ++kk) {
        const int c = c4 * 4 + kk;
        float wl0 = Wl0s[c * 64 + j], wl1 = Wl1s[c * 64 + j];
        float ws0 = Wsc0s[c * 64 + j], ws1 = Wsc1s[c * 64 + j];
        A0 = fmaf(reinterpret_cast<const float*>(&m0v)[kk], wl0, A0);
        A1x = fmaf(reinterpret_cast<const float*>(&mvx)[kk], wl1, A1x);
        A1y = fmaf(reinterpret_cast<const float*>(&mvy)[kk], wl1, A1y);
        A1z = fmaf(reinterpret_cast<const float*>(&mvz)[kk], wl1, A1z);
        sc0 = fmaf(reinterpret_cast<const float*>(&h0v)[kk], ws0, sc0);
        float hx = st[320 + 3 * c + 0];
        float hy = st[320 + 3 * c + 1];
        float hz = st[320 + 3 * c + 2];
        sc1x = fmaf(hx, ws1, sc1x);
        sc1y = fmaf(hy, ws1, sc1y);
        sc1z = fmaf(hz, ws1, sc1z);
      }
    }
    float vv = A1x * A1x + A1y * A1y + A1z * A1z;
    float A02 = A0 * A0;
    float B0 = c00 * A0 + c01 * A02 + c02 * vv + c03 * A02 * A0 + c04 * A0 * vv;
    float sB = c1.x + c1.y * A0 + c1.z * A02 + c1.w * vv;
    float B1x = sB * A1x, B1y = sB * A1y, B1z = sB * A1z;
    st[512 + j] = B0;
    st[576 + j] = B1x;
    st[640 + j] = B1y;
    st[704 + j] = B1z;
    __syncthreads();
    float o0 = sc0, o1x = sc1x, o1y = sc1y, o1z = sc1z;
    for (int c4 = 0; c4 < 16; ++c4) {
      float4 b0v = *reinterpret_cast<const float4*>(st + 512 + c4 * 4);
      float4 bvx = *reinterpret_cast<const float4*>(st + 576 + c4 * 4);
      float4 bvy = *reinterpret_cast<const float4*>(st + 640 + c4 * 4);
      float4 bvz = *reinterpret_cast<const float4*>(st + 704 + c4 * 4);
#pragma unroll
      for (int kk = 0; kk < 4; ++kk) {
        const int c = c4 * 4 + kk;
        float wb0 = WB0[c * 64 + j], wb1 = WB1[c * 64 + j];
        o0 = fmaf(reinterpret_cast<const float*>(&b0v)[kk], wb0, o0);
        o1x = fmaf(reinterpret_cast<const float*>(&bvx)[kk], wb1, o1x);
        o1y = fmaf(reinterpret_cast<const float*>(&bvy)[kk], wb1, o1y);
        o1z = fmaf(reinterpret_cast<const float*>(&bvz)[kk], wb1, o1z);
      }
    }
    float* orow = out + (size_t)n * 256;
    orow[j] = o0;
    orow[64 + 3 * j + 0] = o1x;
    orow[64 + 3 * j + 1] = o1y;
    orow[64 + 3 * j + 2] = o1z;
    s_sum0 += o0;
    s_sq0 = fmaf(o0, o0, s_sq0);
    s_sum1 += o1x * o1x + o1y * o1y + o1z * o1z;
    __syncthreads();
  }
  // block-reduce stats, one atomic set per block
  __syncthreads();
  st[j] = s_sum0;
  st[64 + j] = s_sq0;
  st[128 + j] = s_sum1;
  __syncthreads();
  if (w == 0) {
    float v0 = 0, v1 = 0, v2 = 0;
#pragma unroll
    for (int ww = 0; ww < 4; ++ww) {
      v0 += stw[ww * 768 + j];
      v1 += stw[ww * 768 + 64 + j];
      v2 += stw[ww * 768 + 128 + j];
    }
    atomicAdd(stat + j, v0);
    atomicAdd(stat + 64 + j, v1);
    atomicAdd(stat + 128 + j, v2);
  }
}

// ------------- Kernel D: finalize statistics (1 block, 64 threads) ----------
__global__ void kstat(const float* __restrict__ stat_in,
                      float* __restrict__ stat_out,
                      const float* __restrict__ gamma0,
                      const float* __restrict__ gamma1) {
  const int j = threadIdx.x;
  const float invN = 1.0f / (float)NN;
  float mu = stat_in[j] * invN;
  float var = stat_in[64 + j] * invN - mu * mu;
  float s0 = rsqrtf(var + 1e-5f) * gamma0[j];
  float nr = stat_in[128 + j] * (invN / 3.0f);
  float s1 = rsqrtf(nr + 1e-5f) * gamma1[j];
  stat_out[j] = mu;
  stat_out[64 + j] = s0;
  stat_out[128 + j] = s1;
}

// ------------- Kernel E: normalize d_out in place ----------
__global__ __launch_bounds__(256) void knorm(float* __restrict__ out,
                                             const float* __restrict__ stat,
                                             const float* __restrict__ beta0) {
  const int w = threadIdx.x >> 6, j = threadIdx.x & 63;
  const int n = blockIdx.x * 4 + w;
  const float mu = stat[192 + j], s0 = stat[256 + j], s1 = stat[320 + j];
  const float b0 = beta0[j];
  float* orow = out + (size_t)n * 256;
  orow[j] = (orow[j] - mu) * s0 + b0;
#pragma unroll
  for (int x = 0; x < 3; ++x) orow[64 + 3 * j + x] *= s1;
}

extern "C" void kernel_launch(void* const* d_in, const int* in_sizes, int n_in,
                              void* d_out, int out_size, void* d_ws,
                              size_t ws_size, hipStream_t stream) {
  (void)in_sizes; (void)n_in; (void)out_size; (void)ws_size;
  const float* h = (const float*)d_in[0];
  const int* eidx = (const int*)d_in[1];
  const float* esh = (const float*)d_in[2];
  const float* erbf = (const float*)d_in[3];
  const float* Wup0 = (const float*)d_in[4];
  const float* Wup1 = (const float*)d_in[5];
  const float* M1 = (const float*)d_in[6];
  const float* M2 = (const float*)d_in[7];
  const float* M3 = (const float*)d_in[8];
  const float* M4 = (const float*)d_in[9];
  const float* Wl0 = (const float*)d_in[10];
  const float* Wl1 = (const float*)d_in[11];
  const float* Wsc0 = (const float*)d_in[12];
  const float* Wsc1 = (const float*)d_in[13];
  const float* Wc0 = (const float*)d_in[14];
  const float* Wc1 = (const float*)d_in[15];
  const float* WB0 = (const float*)d_in[16];
  const float* WB1 = (const float*)d_in[17];
  const float* gamma0 = (const float*)d_in[18];
  const float* beta0 = (const float*)d_in[19];
  const float* gamma1 = (const float*)d_in[20];

  float* ws = (float*)d_ws;
  float* up0 = ws;                      // N*64
  float* up1 = ws + (size_t)NN * 64;    // N*192 (layout (n, x, c))
  float* msg0 = ws + (size_t)NN * 256;  // N*64
  float* msg1 = ws + (size_t)NN * 320;  // N*192 (layout (n, x, c))
  float* stat = ws + (size_t)NN * 512;  // 384 floats
  float* outf = (float*)d_out;

  // zero message accumulators + stats every call (atomics accumulate)
  hipMemsetAsync(msg0, 0, ((size_t)NN * 256 + 384) * sizeof(float), stream);

  hipFuncSetAttribute((const void*)knode,
                      hipFuncAttributeMaxDynamicSharedMemorySize, 77824);

  kup<<<NN / 4, 256, 0, stream>>>(h, Wup0, Wup1, up0, up1);
  kedge<<<512, 512, 0, stream>>>(erbf, eidx, esh, M1, M2, M3, M4, up0, up1,
                                 msg0, msg1);
  knode<<<1024, 256, 77824, stream>>>(msg0, msg1, h, Wl0, Wl1, Wsc0, Wsc1, Wc0,
                                      Wc1, WB0, WB1, outf, stat);
  kstat<<<1, 64, 0, stream>>>(stat, stat + 192, gamma0, gamma1);
  knorm<<<NN / 4, 256, 0, stream>>>(outf, stat, beta0);
}

// Round 4
// 768.562 us; speedup vs baseline: 1.1397x; 1.1397x over previous
//
#include <hip/hip_runtime.h>
#include <math.h>

#define NN 50000
#define NE 500000

typedef __attribute__((ext_vector_type(8))) short bf16x8;
typedef __attribute__((ext_vector_type(4))) float f32x4;

__device__ __forceinline__ float silu_f(float x) {
  return x / (1.0f + __expf(-x));
}
// fp32 -> bf16 (RNE)
__device__ __forceinline__ unsigned short f2bf(float x) {
  union { float f; unsigned u; } v;
  v.f = x;
  unsigned r = v.u + 0x7fffu + ((v.u >> 16) & 1u);
  return (unsigned short)(r >> 16);
}
// swizzled index into a [rows][64] bf16 tile: XOR 16B-unit with row&7
__device__ __forceinline__ int swz64(int row, int col) {
  return row * 64 + ((((col >> 3) ^ (row & 7)) << 3) | (col & 7));
}
// swizzled index into a [rows][32] bf16 tile: XOR 16B-unit with row&3
__device__ __forceinline__ int swz32(int row, int col) {
  return row * 32 + ((((col >> 3) ^ (row & 3)) << 3) | (col & 7));
}

// ---------- Sort kernels: counting sort of edges by receiver ----------
__global__ __launch_bounds__(256) void ksort1(const int* __restrict__ eidx,
                                              int* __restrict__ hist) {
  int e = blockIdx.x * 256 + threadIdx.x;
  if (e < NE) atomicAdd(&hist[eidx[NE + e]], 1);
}

__global__ __launch_bounds__(256) void ksort2(const int* __restrict__ hist,
                                              int* __restrict__ cursor) {
  __shared__ int bs[256];
  const int t = threadIdx.x;
  const int CH = (NN + 255) / 256;  // 196
  const int lo = t * CH, hi = (lo + CH < NN) ? lo + CH : NN;
  int s = 0;
  for (int i = lo; i < hi; ++i) s += hist[i];
  bs[t] = s;
  __syncthreads();
  for (int off = 1; off < 256; off <<= 1) {
    int v = (t >= off) ? bs[t - off] : 0;
    __syncthreads();
    bs[t] += v;
    __syncthreads();
  }
  int run = bs[t] - s;  // exclusive prefix over chunks
  for (int i = lo; i < hi; ++i) {
    cursor[i] = run;
    run += hist[i];
  }
}

__global__ __launch_bounds__(256) void ksort3(const int* __restrict__ eidx,
                                              int* __restrict__ cursor,
                                              int* __restrict__ perm) {
  int e = blockIdx.x * 256 + threadIdx.x;
  if (e < NE) {
    int p = atomicAdd(&cursor[eidx[NE + e]], 1);
    perm[p] = e;
  }
}

// ---------------- Kernel A: up0 = h0@Wup0, up1[x] = h1[:,:,x]@Wup1 ----------
__global__ __launch_bounds__(256) void kup(
    const float* __restrict__ h, const float* __restrict__ Wup0,
    const float* __restrict__ Wup1, float* __restrict__ up0,
    float* __restrict__ up1) {
  __shared__ float shd[4][256];
  const int w = threadIdx.x >> 6, j = threadIdx.x & 63;
  const int n = blockIdx.x * 4 + w;
  const float* hr = h + (size_t)n * 256;
#pragma unroll
  for (int t = 0; t < 4; ++t) shd[w][t * 64 + j] = hr[t * 64 + j];
  // shd[w] is wave-private: no barrier needed
  float a0 = 0.f, ax = 0.f, ay = 0.f, az = 0.f;
#pragma unroll 8
  for (int c = 0; c < 64; ++c) {
    float h0 = shd[w][c];
    float hx = shd[w][64 + 3 * c + 0];
    float hy = shd[w][64 + 3 * c + 1];
    float hz = shd[w][64 + 3 * c + 2];
    float w0 = Wup0[c * 64 + j];
    float w1 = Wup1[c * 64 + j];
    a0 = fmaf(h0, w0, a0);
    ax = fmaf(hx, w1, ax);
    ay = fmaf(hy, w1, ay);
    az = fmaf(hz, w1, az);
  }
  up0[(size_t)n * 64 + j] = a0;
  float* u1 = up1 + (size_t)n * 192 + j;
  u1[0] = ax;
  u1[64] = ay;
  u1[128] = az;
}

// ------------- Kernel B: MFMA edge MLP + messages + merged atomic scatter ----
// Edges processed in receiver-sorted order (perm); consecutive same-receiver
// messages are merged in registers before the atomicAdd flush.
__global__ __launch_bounds__(512) void kedge(
    const float* __restrict__ rbf, const int* __restrict__ eidx,
    const float* __restrict__ esh, const float* __restrict__ M1,
    const float* __restrict__ M2, const float* __restrict__ M3,
    const float* __restrict__ M4, const float* __restrict__ up0,
    const float* __restrict__ up1, const int* __restrict__ perm,
    float* __restrict__ msg0, float* __restrict__ msg1) {
  __shared__ unsigned short M1t[64 * 32];    // [out 64][in 32 (16 zero-pad)]
  __shared__ unsigned short M2t[64 * 64];    // [out][in]
  __shared__ unsigned short M3t[64 * 64];
  __shared__ unsigned short M4t[256 * 64];   // [out 256][in 64]
  __shared__ unsigned short actS[8][16 * 64];  // per-wave [edge 16][ch 64]
  const int tid = threadIdx.x;
  const int w = tid >> 6, l = tid & 63;
  const int c = l & 15, q = l >> 4;

  // ---- stage weights: coalesced global read, transposed+swizzled LDS write --
  for (int i = tid; i < 2048; i += 512) {
    int o = i >> 5, k = i & 31;
    M1t[swz32(o, k)] = (k < 16) ? f2bf(M1[k * 64 + o]) : (unsigned short)0;
  }
  for (int i = tid; i < 4096; i += 512) {
    int k = i >> 6, o = i & 63;
    M2t[swz64(o, k)] = f2bf(M2[i]);
    M3t[swz64(o, k)] = f2bf(M3[i]);
  }
  for (int i = tid; i < 16384; i += 512) {
    int k = i >> 8, o = i & 255;
    M4t[swz64(o, k)] = f2bf(M4[i]);
  }
  __syncthreads();

  unsigned short* act = actS[w];
  const float inv3 = 0.57735026918962576f;
  const int NW = NE / 16;  // 31250 wave-groups of 16 sorted slots

  for (int grp = blockIdx.x; grp < (NW + 7) / 8; grp += gridDim.x) {
    const int gw = grp * 8 + w;
    if (gw >= NW) continue;
    const int eb = gw * 16;

    // ---- L1: rbf[16e][16] (K zero-padded to 32) -> act[16e][64] ----
    bf16x8 a1 = {};
    if (q < 2) {
      const int pec = perm[eb + c];
      const float* p = rbf + (size_t)pec * 16 + q * 8;
      float4 f0 = *reinterpret_cast<const float4*>(p);
      float4 f1 = *reinterpret_cast<const float4*>(p + 4);
      a1[0] = (short)f2bf(f0.x); a1[1] = (short)f2bf(f0.y);
      a1[2] = (short)f2bf(f0.z); a1[3] = (short)f2bf(f0.w);
      a1[4] = (short)f2bf(f1.x); a1[5] = (short)f2bf(f1.y);
      a1[6] = (short)f2bf(f1.z); a1[7] = (short)f2bf(f1.w);
    }
    f32x4 acc[4];
#pragma unroll
    for (int nt = 0; nt < 4; ++nt) {
      int n = nt * 16 + c;
      bf16x8 b = *reinterpret_cast<const bf16x8*>(&M1t[n * 32 + ((q ^ (n & 3)) << 3)]);
      f32x4 z = {0.f, 0.f, 0.f, 0.f};
      acc[nt] = __builtin_amdgcn_mfma_f32_16x16x32_bf16(a1, b, z, 0, 0, 0);
    }
#pragma unroll
    for (int nt = 0; nt < 4; ++nt)
#pragma unroll
      for (int r = 0; r < 4; ++r)
        act[swz64(4 * q + r, nt * 16 + c)] = f2bf(silu_f(acc[nt][r]));

    // ---- L2: act -> act (64->64) ----
    {
      bf16x8 a0 = *reinterpret_cast<const bf16x8*>(&act[c * 64 + (((0 + q) ^ (c & 7)) << 3)]);
      bf16x8 a1b = *reinterpret_cast<const bf16x8*>(&act[c * 64 + (((4 + q) ^ (c & 7)) << 3)]);
#pragma unroll
      for (int nt = 0; nt < 4; ++nt) {
        int n = nt * 16 + c;
        bf16x8 b0 = *reinterpret_cast<const bf16x8*>(&M2t[n * 64 + (((0 + q) ^ (n & 7)) << 3)]);
        bf16x8 b1 = *reinterpret_cast<const bf16x8*>(&M2t[n * 64 + (((4 + q) ^ (n & 7)) << 3)]);
        f32x4 z = {0.f, 0.f, 0.f, 0.f};
        acc[nt] = __builtin_amdgcn_mfma_f32_16x16x32_bf16(a0, b0, z, 0, 0, 0);
        acc[nt] = __builtin_amdgcn_mfma_f32_16x16x32_bf16(a1b, b1, acc[nt], 0, 0, 0);
      }
#pragma unroll
      for (int nt = 0; nt < 4; ++nt)
#pragma unroll
        for (int r = 0; r < 4; ++r)
          act[swz64(4 * q + r, nt * 16 + c)] = f2bf(silu_f(acc[nt][r]));
    }
    // ---- L3: act -> act (64->64) ----
    {
      bf16x8 a0 = *reinterpret_cast<const bf16x8*>(&act[c * 64 + (((0 + q) ^ (c & 7)) << 3)]);
      bf16x8 a1b = *reinterpret_cast<const bf16x8*>(&act[c * 64 + (((4 + q) ^ (c & 7)) << 3)]);
#pragma unroll
      for (int nt = 0; nt < 4; ++nt) {
        int n = nt * 16 + c;
        bf16x8 b0 = *reinterpret_cast<const bf16x8*>(&M3t[n * 64 + (((0 + q) ^ (n & 7)) << 3)]);
        bf16x8 b1 = *reinterpret_cast<const bf16x8*>(&M3t[n * 64 + (((4 + q) ^ (n & 7)) << 3)]);
        f32x4 z = {0.f, 0.f, 0.f, 0.f};
        acc[nt] = __builtin_amdgcn_mfma_f32_16x16x32_bf16(a0, b0, z, 0, 0, 0);
        acc[nt] = __builtin_amdgcn_mfma_f32_16x16x32_bf16(a1b, b1, acc[nt], 0, 0, 0);
      }
#pragma unroll
      for (int nt = 0; nt < 4; ++nt)
#pragma unroll
        for (int r = 0; r < 4; ++r)
          act[swz64(4 * q + r, nt * 16 + c)] = f2bf(silu_f(acc[nt][r]));
    }
    // ---- L4: act -> tpw[16e][256] kept in registers (no silu) ----
    f32x4 t[16];
    {
      bf16x8 a0 = *reinterpret_cast<const bf16x8*>(&act[c * 64 + (((0 + q) ^ (c & 7)) << 3)]);
      bf16x8 a1b = *reinterpret_cast<const bf16x8*>(&act[c * 64 + (((4 + q) ^ (c & 7)) << 3)]);
#pragma unroll
      for (int nt = 0; nt < 16; ++nt) {
        int n = nt * 16 + c;
        bf16x8 b0 = *reinterpret_cast<const bf16x8*>(&M4t[n * 64 + (((0 + q) ^ (n & 7)) << 3)]);
        bf16x8 b1 = *reinterpret_cast<const bf16x8*>(&M4t[n * 64 + (((4 + q) ^ (n & 7)) << 3)]);
        f32x4 z = {0.f, 0.f, 0.f, 0.f};
        t[nt] = __builtin_amdgcn_mfma_f32_16x16x32_bf16(a0, b0, z, 0, 0, 0);
        t[nt] = __builtin_amdgcn_mfma_f32_16x16x32_bf16(a1b, b1, t[nt], 0, 0, 0);
      }
    }
    // ---- per-lane metadata for its 4 consecutive sorted edges ----
    int sn[4], rvv[4];
    float4 shv[4];
#pragma unroll
    for (int r = 0; r < 4; ++r) {
      const int e2 = perm[eb + 4 * q + r];
      sn[r] = eidx[e2];
      rvv[r] = eidx[NE + e2];
      shv[r] = *reinterpret_cast<const float4*>(esh + (size_t)e2 * 4);
    }
    // ---- messages + run-length-merged atomic scatter ----
#pragma unroll
    for (int j2 = 0; j2 < 4; ++j2) {
      const int ch = j2 * 16 + c;
      float acc0 = 0.f, accx = 0.f, accy = 0.f, accz = 0.f;
      int cur = rvv[0];
#pragma unroll
      for (int r = 0; r < 4; ++r) {
        const float* u0 = up0 + (size_t)sn[r] * 64;
        const float* u1 = up1 + (size_t)sn[r] * 192;
        float x0 = u0[ch];
        float xx = u1[ch], xy = u1[64 + ch], xz = u1[128 + ch];
        float t0v = t[j2][r], t1v = t[4 + j2][r];
        float t2v = t[8 + j2][r], t3v = t[12 + j2][r];
        float4 sh4 = shv[r];
        float dot = xx * sh4.y + xy * sh4.z + xz * sh4.w;
        float m0 = t0v * x0 * sh4.x + t3v * dot * inv3;
        float a1v = t1v * x0, b1v = t2v * sh4.x;
        float m1x = fmaf(a1v, sh4.y, b1v * xx);
        float m1y = fmaf(a1v, sh4.z, b1v * xy);
        float m1z = fmaf(a1v, sh4.w, b1v * xz);
        if (rvv[r] != cur) {
          atomicAdd(msg0 + (size_t)cur * 64 + ch, acc0);
          atomicAdd(msg1 + (size_t)cur * 192 + ch, accx);
          atomicAdd(msg1 + (size_t)cur * 192 + 64 + ch, accy);
          atomicAdd(msg1 + (size_t)cur * 192 + 128 + ch, accz);
          cur = rvv[r];
          acc0 = accx = accy = accz = 0.f;
        }
        acc0 += m0;
        accx += m1x;
        accy += m1y;
        accz += m1z;
      }
      atomicAdd(msg0 + (size_t)cur * 64 + ch, acc0);
      atomicAdd(msg1 + (size_t)cur * 192 + ch, accx);
      atomicAdd(msg1 + (size_t)cur * 192 + 64 + ch, accy);
      atomicAdd(msg1 + (size_t)cur * 192 + 128 + ch, accz);
    }
  }
}

// ------------- Kernel C: node linear mixes + polynomial + output GEMVs + stats --
// 512 threads (8 waves share staged weights); st is wave-private -> no
// in-loop barriers.
__global__ __launch_bounds__(512) void knode(
    const float* __restrict__ msg0, const float* __restrict__ msg1,
    const float* __restrict__ h, const float* __restrict__ Wl0,
    const float* __restrict__ Wl1, const float* __restrict__ Wsc0,
    const float* __restrict__ Wsc1, const float* __restrict__ Wc0,
    const float* __restrict__ Wc1, const float* __restrict__ WB0,
    const float* __restrict__ WB1, float* __restrict__ out,
    float* __restrict__ stat) {
  extern __shared__ float lds[];
  float* Wl0s = lds;           // 4096
  float* Wl1s = lds + 4096;
  float* Wsc0s = lds + 8192;
  float* Wsc1s = lds + 12288;
  float* stw = lds + 16384;    // 8 waves * 768
  const int tid = threadIdx.x, w = tid >> 6, j = tid & 63;
  for (int i = tid; i < 4096; i += 512) {
    Wl0s[i] = Wl0[i];
    Wl1s[i] = Wl1[i];
    Wsc0s[i] = Wsc0[i];
    Wsc1s[i] = Wsc1[i];
  }
  __syncthreads();
  float* st = stw + w * 768;
  float s_sum0 = 0.f, s_sq0 = 0.f, s_sum1 = 0.f;
  const float c00 = Wc0[j * 5 + 0], c01 = Wc0[j * 5 + 1], c02 = Wc0[j * 5 + 2],
              c03 = Wc0[j * 5 + 3], c04 = Wc0[j * 5 + 4];
  const float4 c1 = *reinterpret_cast<const float4*>(Wc1 + j * 4);

  for (int grp = blockIdx.x; grp < (NN / 8); grp += gridDim.x) {
    const int n = grp * 8 + w;
    st[j] = msg0[(size_t)n * 64 + j];
#pragma unroll
    for (int x = 0; x < 3; ++x)
      st[64 + x * 64 + j] = msg1[(size_t)n * 192 + x * 64 + j];
#pragma unroll
    for (int t = 0; t < 4; ++t)
      st[256 + t * 64 + j] = h[(size_t)n * 256 + t * 64 + j];
    float A0 = 0, A1x = 0, A1y = 0, A1z = 0, sc0 = 0, sc1x = 0, sc1y = 0, sc1z = 0;
    for (int c4 = 0; c4 < 16; ++c4) {
      float4 m0v = *reinterpret_cast<const float4*>(st + c4 * 4);
      float4 mvx = *reinterpret_cast<const float4*>(st + 64 + c4 * 4);
      float4 mvy = *reinterpret_cast<const float4*>(st + 128 + c4 * 4);
      float4 mvz = *reinterpret_cast<const float4*>(st + 192 + c4 * 4);
      float4 h0v = *reinterpret_cast<const float4*>(st + 256 + c4 * 4);
#pragma unroll
      for (int kk = 0; kk < 4; ++kk) {
        const int c = c4 * 4 + kk;
        float wl0 = Wl0s[c * 64 + j], wl1 = Wl1s[c * 64 + j];
        float ws0 = Wsc0s[c * 64 + j], ws1 = Wsc1s[c * 64 + j];
        A0 = fmaf(reinterpret_cast<const float*>(&m0v)[kk], wl0, A0);
        A1x = fmaf(reinterpret_cast<const float*>(&mvx)[kk], wl1, A1x);
        A1y = fmaf(reinterpret_cast<const float*>(&mvy)[kk], wl1, A1y);
        A1z = fmaf(reinterpret_cast<const float*>(&mvz)[kk], wl1, A1z);
        sc0 = fmaf(reinterpret_cast<const float*>(&h0v)[kk], ws0, sc0);
        float hx = st[320 + 3 * c + 0];
        float hy = st[320 + 3 * c + 1];
        float hz = st[320 + 3 * c + 2];
        sc1x = fmaf(hx, ws1, sc1x);
        sc1y = fmaf(hy, ws1, sc1y);
        sc1z = fmaf(hz, ws1, sc1z);
      }
    }
    float vv = A1x * A1x + A1y * A1y + A1z * A1z;
    float A02 = A0 * A0;
    float B0 = c00 * A0 + c01 * A02 + c02 * vv + c03 * A02 * A0 + c04 * A0 * vv;
    float sB = c1.x + c1.y * A0 + c1.z * A02 + c1.w * vv;
    float B1x = sB * A1x, B1y = sB * A1y, B1z = sB * A1z;
    st[512 + j] = B0;
    st[576 + j] = B1x;
    st[640 + j] = B1y;
    st[704 + j] = B1z;
    float o0 = sc0, o1x = sc1x, o1y = sc1y, o1z = sc1z;
    for (int c4 = 0; c4 < 16; ++c4) {
      float4 b0v = *reinterpret_cast<const float4*>(st + 512 + c4 * 4);
      float4 bvx = *reinterpret_cast<const float4*>(st + 576 + c4 * 4);
      float4 bvy = *reinterpret_cast<const float4*>(st + 640 + c4 * 4);
      float4 bvz = *reinterpret_cast<const float4*>(st + 704 + c4 * 4);
#pragma unroll
      for (int kk = 0; kk < 4; ++kk) {
        const int c = c4 * 4 + kk;
        float wb0 = WB0[c * 64 + j], wb1 = WB1[c * 64 + j];
        o0 = fmaf(reinterpret_cast<const float*>(&b0v)[kk], wb0, o0);
        o1x = fmaf(reinterpret_cast<const float*>(&bvx)[kk], wb1, o1x);
        o1y = fmaf(reinterpret_cast<const float*>(&bvy)[kk], wb1, o1y);
        o1z = fmaf(reinterpret_cast<const float*>(&bvz)[kk], wb1, o1z);
      }
    }
    float* orow = out + (size_t)n * 256;
    orow[j] = o0;
    orow[64 + 3 * j + 0] = o1x;
    orow[64 + 3 * j + 1] = o1y;
    orow[64 + 3 * j + 2] = o1z;
    s_sum0 += o0;
    s_sq0 = fmaf(o0, o0, s_sq0);
    s_sum1 += o1x * o1x + o1y * o1y + o1z * o1z;
  }
  // block-reduce stats, one atomic set per block
  __syncthreads();
  st[j] = s_sum0;
  st[64 + j] = s_sq0;
  st[128 + j] = s_sum1;
  __syncthreads();
  if (w == 0) {
    float v0 = 0, v1 = 0, v2 = 0;
#pragma unroll
    for (int ww = 0; ww < 8; ++ww) {
      v0 += stw[ww * 768 + j];
      v1 += stw[ww * 768 + 64 + j];
      v2 += stw[ww * 768 + 128 + j];
    }
    atomicAdd(stat + j, v0);
    atomicAdd(stat + 64 + j, v1);
    atomicAdd(stat + 128 + j, v2);
  }
}

// ------------- Kernel D: finalize statistics (1 block, 64 threads) ----------
__global__ void kstat(const float* __restrict__ stat_in,
                      float* __restrict__ stat_out,
                      const float* __restrict__ gamma0,
                      const float* __restrict__ gamma1) {
  const int j = threadIdx.x;
  const float invN = 1.0f / (float)NN;
  float mu = stat_in[j] * invN;
  float var = stat_in[64 + j] * invN - mu * mu;
  float s0 = rsqrtf(var + 1e-5f) * gamma0[j];
  float nr = stat_in[128 + j] * (invN / 3.0f);
  float s1 = rsqrtf(nr + 1e-5f) * gamma1[j];
  stat_out[j] = mu;
  stat_out[64 + j] = s0;
  stat_out[128 + j] = s1;
}

// ------------- Kernel E: normalize d_out in place ----------
__global__ __launch_bounds__(256) void knorm(float* __restrict__ out,
                                             const float* __restrict__ stat,
                                             const float* __restrict__ beta0) {
  const int w = threadIdx.x >> 6, j = threadIdx.x & 63;
  const int n = blockIdx.x * 4 + w;
  const float mu = stat[192 + j], s0 = stat[256 + j], s1 = stat[320 + j];
  const float b0 = beta0[j];
  float* orow = out + (size_t)n * 256;
  orow[j] = (orow[j] - mu) * s0 + b0;
#pragma unroll
  for (int x = 0; x < 3; ++x) orow[64 + 3 * j + x] *= s1;
}

extern "C" void kernel_launch(void* const* d_in, const int* in_sizes, int n_in,
                              void* d_out, int out_size, void* d_ws,
                              size_t ws_size, hipStream_t stream) {
  (void)in_sizes; (void)n_in; (void)out_size; (void)ws_size;
  const float* h = (const float*)d_in[0];
  const int* eidx = (const int*)d_in[1];
  const float* esh = (const float*)d_in[2];
  const float* erbf = (const float*)d_in[3];
  const float* Wup0 = (const float*)d_in[4];
  const float* Wup1 = (const float*)d_in[5];
  const float* M1 = (const float*)d_in[6];
  const float* M2 = (const float*)d_in[7];
  const float* M3 = (const float*)d_in[8];
  const float* M4 = (const float*)d_in[9];
  const float* Wl0 = (const float*)d_in[10];
  const float* Wl1 = (const float*)d_in[11];
  const float* Wsc0 = (const float*)d_in[12];
  const float* Wsc1 = (const float*)d_in[13];
  const float* Wc0 = (const float*)d_in[14];
  const float* Wc1 = (const float*)d_in[15];
  const float* WB0 = (const float*)d_in[16];
  const float* WB1 = (const float*)d_in[17];
  const float* gamma0 = (const float*)d_in[18];
  const float* beta0 = (const float*)d_in[19];
  const float* gamma1 = (const float*)d_in[20];

  float* ws = (float*)d_ws;
  float* up0 = ws;                      // N*64
  float* up1 = ws + (size_t)NN * 64;    // N*192 (layout (n, x, c))
  float* msg0 = ws + (size_t)NN * 256;  // N*64
  float* msg1 = ws + (size_t)NN * 320;  // N*192 (layout (n, x, c))
  float* stat = ws + (size_t)NN * 512;  // 384 floats
  float* outf = (float*)d_out;

  // sort scratch lives in d_out (overwritten by knode/knorm afterwards)
  int* hist = (int*)d_out;        // NN
  int* cursor = hist + NN;        // NN
  int* perm = cursor + NN;        // NE

  // zero message accumulators + stats + hist every call (atomics accumulate)
  hipMemsetAsync(msg0, 0, ((size_t)NN * 256 + 384) * sizeof(float), stream);
  hipMemsetAsync(hist, 0, (size_t)NN * sizeof(int), stream);

  hipFuncSetAttribute((const void*)knode,
                      hipFuncAttributeMaxDynamicSharedMemorySize, 90112);

  const int EG = (NE + 255) / 256;
  ksort1<<<EG, 256, 0, stream>>>(eidx, hist);
  ksort2<<<1, 256, 0, stream>>>(hist, cursor);
  ksort3<<<EG, 256, 0, stream>>>(eidx, cursor, perm);
  kup<<<NN / 4, 256, 0, stream>>>(h, Wup0, Wup1, up0, up1);
  kedge<<<512, 512, 0, stream>>>(erbf, eidx, esh, M1, M2, M3, M4, up0, up1,
                                 perm, msg0, msg1);
  knode<<<1024, 512, 90112, stream>>>(msg0, msg1, h, Wl0, Wl1, Wsc0, Wsc1, Wc0,
                                      Wc1, WB0, WB1, outf, stat);
  kstat<<<1, 64, 0, stream>>>(stat, stat + 192, gamma0, gamma1);
  knorm<<<NN / 4, 256, 0, stream>>>(outf, stat, beta0);
}

// Round 8
// 748.800 us; speedup vs baseline: 1.1698x; 1.0264x over previous
//
#include <hip/hip_runtime.h>
#include <math.h>

#define NN 50000
#define NE 500000

typedef __attribute__((ext_vector_type(8))) short bf16x8;
typedef __attribute__((ext_vector_type(4))) float f32x4;

__device__ __forceinline__ float silu_f(float x) {
  return x / (1.0f + __expf(-x));
}
// fp32 -> bf16 (RNE)
__device__ __forceinline__ unsigned short f2bf(float x) {
  union { float f; unsigned u; } v;
  v.f = x;
  unsigned r = v.u + 0x7fffu + ((v.u >> 16) & 1u);
  return (unsigned short)(r >> 16);
}
// swizzled index into a [rows][64] bf16 tile: XOR 16B-unit with row&7
__device__ __forceinline__ int swz64(int row, int col) {
  return row * 64 + ((((col >> 3) ^ (row & 7)) << 3) | (col & 7));
}
// swizzled index into a [rows][32] bf16 tile: XOR 16B-unit with row&3
__device__ __forceinline__ int swz32(int row, int col) {
  return row * 32 + ((((col >> 3) ^ (row & 3)) << 3) | (col & 7));
}

// ---------- Sort kernels: counting sort of edges by receiver ----------
__global__ __launch_bounds__(256) void ksort1(const int* __restrict__ eidx,
                                              int* __restrict__ hist) {
  int e = blockIdx.x * 256 + threadIdx.x;
  if (e < NE) atomicAdd(&hist[eidx[NE + e]], 1);
}

__global__ __launch_bounds__(256) void ksort2(const int* __restrict__ hist,
                                              int* __restrict__ cursor) {
  __shared__ int bs[256];
  const int t = threadIdx.x;
  const int CH = (NN + 255) / 256;  // 196
  const int lo = t * CH, hi = (lo + CH < NN) ? lo + CH : NN;
  int s = 0;
  for (int i = lo; i < hi; ++i) s += hist[i];
  bs[t] = s;
  __syncthreads();
  for (int off = 1; off < 256; off <<= 1) {
    int v = (t >= off) ? bs[t - off] : 0;
    __syncthreads();
    bs[t] += v;
    __syncthreads();
  }
  int run = bs[t] - s;  // exclusive prefix over chunks
  for (int i = lo; i < hi; ++i) {
    cursor[i] = run;
    run += hist[i];
  }
}

__global__ __launch_bounds__(256) void ksort3(const int* __restrict__ eidx,
                                              int* __restrict__ cursor,
                                              int* __restrict__ perm) {
  int e = blockIdx.x * 256 + threadIdx.x;
  if (e < NE) {
    int p = atomicAdd(&cursor[eidx[NE + e]], 1);
    perm[p] = e;
  }
}

// ---------------- Kernel A: up0 = h0@Wup0, up1[x] = h1[:,:,x]@Wup1 ----------
__global__ __launch_bounds__(256) void kup(
    const float* __restrict__ h, const float* __restrict__ Wup0,
    const float* __restrict__ Wup1, float* __restrict__ up0,
    float* __restrict__ up1) {
  __shared__ float shd[4][256];
  const int w = threadIdx.x >> 6, j = threadIdx.x & 63;
  const int n = blockIdx.x * 4 + w;
  const float* hr = h + (size_t)n * 256;
#pragma unroll
  for (int t = 0; t < 4; ++t) shd[w][t * 64 + j] = hr[t * 64 + j];
  // shd[w] is wave-private AND lane j only re-reads values via broadcast
  // pattern below; keep as in validated R4 build.
  float a0 = 0.f, ax = 0.f, ay = 0.f, az = 0.f;
#pragma unroll 8
  for (int c = 0; c < 64; ++c) {
    float h0 = shd[w][c];
    float hx = shd[w][64 + 3 * c + 0];
    float hy = shd[w][64 + 3 * c + 1];
    float hz = shd[w][64 + 3 * c + 2];
    float w0 = Wup0[c * 64 + j];
    float w1 = Wup1[c * 64 + j];
    a0 = fmaf(h0, w0, a0);
    ax = fmaf(hx, w1, ax);
    ay = fmaf(hy, w1, ay);
    az = fmaf(hz, w1, az);
  }
  up0[(size_t)n * 64 + j] = a0;
  float* u1 = up1 + (size_t)n * 192 + j;
  u1[0] = ax;
  u1[64] = ay;
  u1[128] = az;
}

// ------------- Kernel B: MFMA edge MLP + messages + merged atomic scatter ----
// R4-exact (validated: absmax 0.75, 328 us).
__global__ __launch_bounds__(512) void kedge(
    const float* __restrict__ rbf, const int* __restrict__ eidx,
    const float* __restrict__ esh, const float* __restrict__ M1,
    const float* __restrict__ M2, const float* __restrict__ M3,
    const float* __restrict__ M4, const float* __restrict__ up0,
    const float* __restrict__ up1, const int* __restrict__ perm,
    float* __restrict__ msg0, float* __restrict__ msg1) {
  __shared__ unsigned short M1t[64 * 32];    // [out 64][in 32 (16 zero-pad)]
  __shared__ unsigned short M2t[64 * 64];    // [out][in]
  __shared__ unsigned short M3t[64 * 64];
  __shared__ unsigned short M4t[256 * 64];   // [out 256][in 64]
  __shared__ unsigned short actS[8][16 * 64];  // per-wave [edge 16][ch 64]
  const int tid = threadIdx.x;
  const int w = tid >> 6, l = tid & 63;
  const int c = l & 15, q = l >> 4;

  for (int i = tid; i < 2048; i += 512) {
    int o = i >> 5, k = i & 31;
    M1t[swz32(o, k)] = (k < 16) ? f2bf(M1[k * 64 + o]) : (unsigned short)0;
  }
  for (int i = tid; i < 4096; i += 512) {
    int k = i >> 6, o = i & 63;
    M2t[swz64(o, k)] = f2bf(M2[i]);
    M3t[swz64(o, k)] = f2bf(M3[i]);
  }
  for (int i = tid; i < 16384; i += 512) {
    int k = i >> 8, o = i & 255;
    M4t[swz64(o, k)] = f2bf(M4[i]);
  }
  __syncthreads();

  unsigned short* act = actS[w];
  const float inv3 = 0.57735026918962576f;
  const int NW = NE / 16;  // 31250

  for (int grp = blockIdx.x; grp < (NW + 7) / 8; grp += gridDim.x) {
    const int gw = grp * 8 + w;
    if (gw >= NW) continue;
    const int eb = gw * 16;

    // ---- L1: rbf[16e][16] (K zero-padded to 32) -> act[16e][64] ----
    bf16x8 a1 = {};
    if (q < 2) {
      const int pec = perm[eb + c];
      const float* p = rbf + (size_t)pec * 16 + q * 8;
      float4 f0 = *reinterpret_cast<const float4*>(p);
      float4 f1 = *reinterpret_cast<const float4*>(p + 4);
      a1[0] = (short)f2bf(f0.x); a1[1] = (short)f2bf(f0.y);
      a1[2] = (short)f2bf(f0.z); a1[3] = (short)f2bf(f0.w);
      a1[4] = (short)f2bf(f1.x); a1[5] = (short)f2bf(f1.y);
      a1[6] = (short)f2bf(f1.z); a1[7] = (short)f2bf(f1.w);
    }
    f32x4 acc[4];
#pragma unroll
    for (int nt = 0; nt < 4; ++nt) {
      int n = nt * 16 + c;
      bf16x8 b = *reinterpret_cast<const bf16x8*>(&M1t[n * 32 + ((q ^ (n & 3)) << 3)]);
      f32x4 z = {0.f, 0.f, 0.f, 0.f};
      acc[nt] = __builtin_amdgcn_mfma_f32_16x16x32_bf16(a1, b, z, 0, 0, 0);
    }
#pragma unroll
    for (int nt = 0; nt < 4; ++nt)
#pragma unroll
      for (int r = 0; r < 4; ++r)
        act[swz64(4 * q + r, nt * 16 + c)] = f2bf(silu_f(acc[nt][r]));

    // ---- L2 ----
    {
      bf16x8 a0 = *reinterpret_cast<const bf16x8*>(&act[c * 64 + (((0 + q) ^ (c & 7)) << 3)]);
      bf16x8 a1b = *reinterpret_cast<const bf16x8*>(&act[c * 64 + (((4 + q) ^ (c & 7)) << 3)]);
#pragma unroll
      for (int nt = 0; nt < 4; ++nt) {
        int n = nt * 16 + c;
        bf16x8 b0 = *reinterpret_cast<const bf16x8*>(&M2t[n * 64 + (((0 + q) ^ (n & 7)) << 3)]);
        bf16x8 b1 = *reinterpret_cast<const bf16x8*>(&M2t[n * 64 + (((4 + q) ^ (n & 7)) << 3)]);
        f32x4 z = {0.f, 0.f, 0.f, 0.f};
        acc[nt] = __builtin_amdgcn_mfma_f32_16x16x32_bf16(a0, b0, z, 0, 0, 0);
        acc[nt] = __builtin_amdgcn_mfma_f32_16x16x32_bf16(a1b, b1, acc[nt], 0, 0, 0);
      }
#pragma unroll
      for (int nt = 0; nt < 4; ++nt)
#pragma unroll
        for (int r = 0; r < 4; ++r)
          act[swz64(4 * q + r, nt * 16 + c)] = f2bf(silu_f(acc[nt][r]));
    }
    // ---- L3 ----
    {
      bf16x8 a0 = *reinterpret_cast<const bf16x8*>(&act[c * 64 + (((0 + q) ^ (c & 7)) << 3)]);
      bf16x8 a1b = *reinterpret_cast<const bf16x8*>(&act[c * 64 + (((4 + q) ^ (c & 7)) << 3)]);
#pragma unroll
      for (int nt = 0; nt < 4; ++nt) {
        int n = nt * 16 + c;
        bf16x8 b0 = *reinterpret_cast<const bf16x8*>(&M3t[n * 64 + (((0 + q) ^ (n & 7)) << 3)]);
        bf16x8 b1 = *reinterpret_cast<const bf16x8*>(&M3t[n * 64 + (((4 + q) ^ (n & 7)) << 3)]);
        f32x4 z = {0.f, 0.f, 0.f, 0.f};
        acc[nt] = __builtin_amdgcn_mfma_f32_16x16x32_bf16(a0, b0, z, 0, 0, 0);
        acc[nt] = __builtin_amdgcn_mfma_f32_16x16x32_bf16(a1b, b1, acc[nt], 0, 0, 0);
      }
#pragma unroll
      for (int nt = 0; nt < 4; ++nt)
#pragma unroll
        for (int r = 0; r < 4; ++r)
          act[swz64(4 * q + r, nt * 16 + c)] = f2bf(silu_f(acc[nt][r]));
    }
    // ---- L4: act -> tpw[16e][256] in registers ----
    f32x4 t[16];
    {
      bf16x8 a0 = *reinterpret_cast<const bf16x8*>(&act[c * 64 + (((0 + q) ^ (c & 7)) << 3)]);
      bf16x8 a1b = *reinterpret_cast<const bf16x8*>(&act[c * 64 + (((4 + q) ^ (c & 7)) << 3)]);
#pragma unroll
      for (int nt = 0; nt < 16; ++nt) {
        int n = nt * 16 + c;
        bf16x8 b0 = *reinterpret_cast<const bf16x8*>(&M4t[n * 64 + (((0 + q) ^ (n & 7)) << 3)]);
        bf16x8 b1 = *reinterpret_cast<const bf16x8*>(&M4t[n * 64 + (((4 + q) ^ (n & 7)) << 3)]);
        f32x4 z = {0.f, 0.f, 0.f, 0.f};
        t[nt] = __builtin_amdgcn_mfma_f32_16x16x32_bf16(a0, b0, z, 0, 0, 0);
        t[nt] = __builtin_amdgcn_mfma_f32_16x16x32_bf16(a1b, b1, t[nt], 0, 0, 0);
      }
    }
    // ---- per-lane metadata for its 4 consecutive sorted edges ----
    int sn[4], rvv[4];
    float4 shv[4];
#pragma unroll
    for (int r = 0; r < 4; ++r) {
      const int e2 = perm[eb + 4 * q + r];
      sn[r] = eidx[e2];
      rvv[r] = eidx[NE + e2];
      shv[r] = *reinterpret_cast<const float4*>(esh + (size_t)e2 * 4);
    }
    // ---- messages + run-length-merged atomic scatter ----
#pragma unroll
    for (int j2 = 0; j2 < 4; ++j2) {
      const int ch = j2 * 16 + c;
      float acc0 = 0.f, accx = 0.f, accy = 0.f, accz = 0.f;
      int cur = rvv[0];
#pragma unroll
      for (int r = 0; r < 4; ++r) {
        const float* u0 = up0 + (size_t)sn[r] * 64;
        const float* u1 = up1 + (size_t)sn[r] * 192;
        float x0 = u0[ch];
        float xx = u1[ch], xy = u1[64 + ch], xz = u1[128 + ch];
        float t0v = t[j2][r], t1v = t[4 + j2][r];
        float t2v = t[8 + j2][r], t3v = t[12 + j2][r];
        float4 sh4 = shv[r];
        float dot = xx * sh4.y + xy * sh4.z + xz * sh4.w;
        float m0 = t0v * x0 * sh4.x + t3v * dot * inv3;
        float a1v = t1v * x0, b1v = t2v * sh4.x;
        float m1x = fmaf(a1v, sh4.y, b1v * xx);
        float m1y = fmaf(a1v, sh4.z, b1v * xy);
        float m1z = fmaf(a1v, sh4.w, b1v * xz);
        if (rvv[r] != cur) {
          atomicAdd(msg0 + (size_t)cur * 64 + ch, acc0);
          atomicAdd(msg1 + (size_t)cur * 192 + ch, accx);
          atomicAdd(msg1 + (size_t)cur * 192 + 64 + ch, accy);
          atomicAdd(msg1 + (size_t)cur * 192 + 128 + ch, accz);
          cur = rvv[r];
          acc0 = accx = accy = accz = 0.f;
        }
        acc0 += m0;
        accx += m1x;
        accy += m1y;
        accz += m1z;
      }
      atomicAdd(msg0 + (size_t)cur * 64 + ch, acc0);
      atomicAdd(msg1 + (size_t)cur * 192 + ch, accx);
      atomicAdd(msg1 + (size_t)cur * 192 + 64 + ch, accy);
      atomicAdd(msg1 + (size_t)cur * 192 + 128 + ch, accz);
    }
  }
}

// ------------- Kernel C: node path, fp32 GEMV, 512 threads, BARRIERED ------
// Cross-lane LDS handoffs (input stage -> GEMV reads; B write -> GEMV2 reads;
// loop-end before restaging) are each fenced with __syncthreads: the no-barrier
// variant is UB (compiler may hoist non-self-aliasing ds_reads past ds_writes)
// and was the best explanation for the R5-R7 failures.
__global__ __launch_bounds__(512) void knode(
    const float* __restrict__ msg0, const float* __restrict__ msg1,
    const float* __restrict__ h, const float* __restrict__ Wl0,
    const float* __restrict__ Wl1, const float* __restrict__ Wsc0,
    const float* __restrict__ Wsc1, const float* __restrict__ Wc0,
    const float* __restrict__ Wc1, const float* __restrict__ WB0,
    const float* __restrict__ WB1, float* __restrict__ out,
    float* __restrict__ stat) {
  extern __shared__ float lds[];
  float* Wl0s = lds;            // 4096
  float* Wl1s = lds + 4096;
  float* Wsc0s = lds + 8192;
  float* Wsc1s = lds + 12288;
  float* WB0s = lds + 16384;
  float* WB1s = lds + 20480;
  float* stw = lds + 24576;     // 8 waves * 768
  const int tid = threadIdx.x, w = tid >> 6, j = tid & 63;
  for (int i = tid; i < 4096; i += 512) {
    Wl0s[i] = Wl0[i];
    Wl1s[i] = Wl1[i];
    Wsc0s[i] = Wsc0[i];
    Wsc1s[i] = Wsc1[i];
    WB0s[i] = WB0[i];
    WB1s[i] = WB1[i];
  }
  __syncthreads();
  float* st = stw + w * 768;
  float s_sum0 = 0.f, s_sq0 = 0.f, s_sum1 = 0.f;
  const float c00 = Wc0[j * 5 + 0], c01 = Wc0[j * 5 + 1], c02 = Wc0[j * 5 + 2],
              c03 = Wc0[j * 5 + 3], c04 = Wc0[j * 5 + 4];
  const float4 c1 = *reinterpret_cast<const float4*>(Wc1 + j * 4);

  for (int grp = blockIdx.x; grp < (NN / 8); grp += gridDim.x) {
    const int n = grp * 8 + w;
    st[j] = msg0[(size_t)n * 64 + j];
#pragma unroll
    for (int x = 0; x < 3; ++x)
      st[64 + x * 64 + j] = msg1[(size_t)n * 192 + x * 64 + j];
#pragma unroll
    for (int t = 0; t < 4; ++t)
      st[256 + t * 64 + j] = h[(size_t)n * 256 + t * 64 + j];
    __syncthreads();
    float A0 = 0, A1x = 0, A1y = 0, A1z = 0, sc0 = 0, sc1x = 0, sc1y = 0, sc1z = 0;
    for (int c4 = 0; c4 < 16; ++c4) {
      float4 m0v = *reinterpret_cast<const float4*>(st + c4 * 4);
      float4 mvx = *reinterpret_cast<const float4*>(st + 64 + c4 * 4);
      float4 mvy = *reinterpret_cast<const float4*>(st + 128 + c4 * 4);
      float4 mvz = *reinterpret_cast<const float4*>(st + 192 + c4 * 4);
      float4 h0v = *reinterpret_cast<const float4*>(st + 256 + c4 * 4);
#pragma unroll
      for (int kk = 0; kk < 4; ++kk) {
        const int c = c4 * 4 + kk;
        float wl0 = Wl0s[c * 64 + j], wl1 = Wl1s[c * 64 + j];
        float ws0 = Wsc0s[c * 64 + j], ws1 = Wsc1s[c * 64 + j];
        A0 = fmaf(reinterpret_cast<const float*>(&m0v)[kk], wl0, A0);
        A1x = fmaf(reinterpret_cast<const float*>(&mvx)[kk], wl1, A1x);
        A1y = fmaf(reinterpret_cast<const float*>(&mvy)[kk], wl1, A1y);
        A1z = fmaf(reinterpret_cast<const float*>(&mvz)[kk], wl1, A1z);
        sc0 = fmaf(reinterpret_cast<const float*>(&h0v)[kk], ws0, sc0);
        float hx = st[320 + 3 * c + 0];
        float hy = st[320 + 3 * c + 1];
        float hz = st[320 + 3 * c + 2];
        sc1x = fmaf(hx, ws1, sc1x);
        sc1y = fmaf(hy, ws1, sc1y);
        sc1z = fmaf(hz, ws1, sc1z);
      }
    }
    float vv = A1x * A1x + A1y * A1y + A1z * A1z;
    float A02 = A0 * A0;
    float B0 = c00 * A0 + c01 * A02 + c02 * vv + c03 * A02 * A0 + c04 * A0 * vv;
    float sB = c1.x + c1.y * A0 + c1.z * A02 + c1.w * vv;
    float B1x = sB * A1x, B1y = sB * A1y, B1z = sB * A1z;
    st[512 + j] = B0;
    st[576 + j] = B1x;
    st[640 + j] = B1y;
    st[704 + j] = B1z;
    __syncthreads();
    float o0 = sc0, o1x = sc1x, o1y = sc1y, o1z = sc1z;
    for (int c4 = 0; c4 < 16; ++c4) {
      float4 b0v = *reinterpret_cast<const float4*>(st + 512 + c4 * 4);
      float4 bvx = *reinterpret_cast<const float4*>(st + 576 + c4 * 4);
      float4 bvy = *reinterpret_cast<const float4*>(st + 640 + c4 * 4);
      float4 bvz = *reinterpret_cast<const float4*>(st + 704 + c4 * 4);
#pragma unroll
      for (int kk = 0; kk < 4; ++kk) {
        const int c = c4 * 4 + kk;
        float wb0 = WB0s[c * 64 + j], wb1 = WB1s[c * 64 + j];
        o0 = fmaf(reinterpret_cast<const float*>(&b0v)[kk], wb0, o0);
        o1x = fmaf(reinterpret_cast<const float*>(&bvx)[kk], wb1, o1x);
        o1y = fmaf(reinterpret_cast<const float*>(&bvy)[kk], wb1, o1y);
        o1z = fmaf(reinterpret_cast<const float*>(&bvz)[kk], wb1, o1z);
      }
    }
    float* orow = out + (size_t)n * 256;
    orow[j] = o0;
    orow[64 + 3 * j + 0] = o1x;
    orow[64 + 3 * j + 1] = o1y;
    orow[64 + 3 * j + 2] = o1z;
    s_sum0 += o0;
    s_sq0 = fmaf(o0, o0, s_sq0);
    s_sum1 += o1x * o1x + o1y * o1y + o1z * o1z;
    __syncthreads();
  }
  // block-reduce stats, one atomic set per block
  __syncthreads();
  st[j] = s_sum0;
  st[64 + j] = s_sq0;
  st[128 + j] = s_sum1;
  __syncthreads();
  if (w == 0) {
    float v0 = 0, v1 = 0, v2 = 0;
#pragma unroll
    for (int ww = 0; ww < 8; ++ww) {
      v0 += stw[ww * 768 + j];
      v1 += stw[ww * 768 + 64 + j];
      v2 += stw[ww * 768 + 128 + j];
    }
    atomicAdd(stat + j, v0);
    atomicAdd(stat + 64 + j, v1);
    atomicAdd(stat + 128 + j, v2);
  }
}

// ------------- Kernel D: finalize statistics (1 block, 64 threads) ----------
__global__ void kstat(const float* __restrict__ stat_in,
                      float* __restrict__ stat_out,
                      const float* __restrict__ gamma0,
                      const float* __restrict__ gamma1) {
  const int j = threadIdx.x;
  const float invN = 1.0f / (float)NN;
  float mu = stat_in[j] * invN;
  float var = stat_in[64 + j] * invN - mu * mu;
  float s0 = rsqrtf(var + 1e-5f) * gamma0[j];
  float nr = stat_in[128 + j] * (invN / 3.0f);
  float s1 = rsqrtf(nr + 1e-5f) * gamma1[j];
  stat_out[j] = mu;
  stat_out[64 + j] = s0;
  stat_out[128 + j] = s1;
}

// ------------- Kernel E: normalize d_out in place ----------
__global__ __launch_bounds__(256) void knorm(float* __restrict__ out,
                                             const float* __restrict__ stat,
                                             const float* __restrict__ beta0) {
  const int w = threadIdx.x >> 6, j = threadIdx.x & 63;
  const int n = blockIdx.x * 4 + w;
  const float mu = stat[192 + j], s0 = stat[256 + j], s1 = stat[320 + j];
  const float b0 = beta0[j];
  float* orow = out + (size_t)n * 256;
  orow[j] = (orow[j] - mu) * s0 + b0;
#pragma unroll
  for (int x = 0; x < 3; ++x) orow[64 + 3 * j + x] *= s1;
}

extern "C" void kernel_launch(void* const* d_in, const int* in_sizes, int n_in,
                              void* d_out, int out_size, void* d_ws,
                              size_t ws_size, hipStream_t stream) {
  (void)in_sizes; (void)n_in; (void)out_size; (void)ws_size;
  const float* h = (const float*)d_in[0];
  const int* eidx = (const int*)d_in[1];
  const float* esh = (const float*)d_in[2];
  const float* erbf = (const float*)d_in[3];
  const float* Wup0 = (const float*)d_in[4];
  const float* Wup1 = (const float*)d_in[5];
  const float* M1 = (const float*)d_in[6];
  const float* M2 = (const float*)d_in[7];
  const float* M3 = (const float*)d_in[8];
  const float* M4 = (const float*)d_in[9];
  const float* Wl0 = (const float*)d_in[10];
  const float* Wl1 = (const float*)d_in[11];
  const float* Wsc0 = (const float*)d_in[12];
  const float* Wsc1 = (const float*)d_in[13];
  const float* Wc0 = (const float*)d_in[14];
  const float* Wc1 = (const float*)d_in[15];
  const float* WB0 = (const float*)d_in[16];
  const float* WB1 = (const float*)d_in[17];
  const float* gamma0 = (const float*)d_in[18];
  const float* beta0 = (const float*)d_in[19];
  const float* gamma1 = (const float*)d_in[20];

  float* ws = (float*)d_ws;
  float* up0 = ws;                      // N*64
  float* up1 = ws + (size_t)NN * 64;    // N*192 (layout (n, x, c))
  float* msg0 = ws + (size_t)NN * 256;  // N*64
  float* msg1 = ws + (size_t)NN * 320;  // N*192 (layout (n, x, c))
  float* stat = ws + (size_t)NN * 512;  // 384 floats
  float* outf = (float*)d_out;

  // sort scratch lives in d_out (overwritten by knode/knorm afterwards)
  int* hist = (int*)d_out;        // NN
  int* cursor = hist + NN;        // NN
  int* perm = cursor + NN;        // NE

  hipMemsetAsync(msg0, 0, ((size_t)NN * 256 + 384) * sizeof(float), stream);
  hipMemsetAsync(hist, 0, (size_t)NN * sizeof(int), stream);

  hipFuncSetAttribute((const void*)knode,
                      hipFuncAttributeMaxDynamicSharedMemorySize, 122880);

  const int EG = (NE + 255) / 256;
  ksort1<<<EG, 256, 0, stream>>>(eidx, hist);
  ksort2<<<1, 256, 0, stream>>>(hist, cursor);
  ksort3<<<EG, 256, 0, stream>>>(eidx, cursor, perm);
  kup<<<NN / 4, 256, 0, stream>>>(h, Wup0, Wup1, up0, up1);
  kedge<<<512, 512, 0, stream>>>(erbf, eidx, esh, M1, M2, M3, M4, up0, up1,
                                 perm, msg0, msg1);
  knode<<<1024, 512, 122880, stream>>>(msg0, msg1, h, Wl0, Wl1, Wsc0, Wsc1,
                                       Wc0, Wc1, WB0, WB1, outf, stat);
  kstat<<<1, 64, 0, stream>>>(stat, stat + 192, gamma0, gamma1);
  knorm<<<NN / 4, 256, 0, stream>>>(outf, stat, beta0);
}